// Round 14
// baseline (262.051 us; speedup 1.0000x reference)
//
#include <hip/hip_runtime.h>
#include <hip/hip_bf16.h>

// Hypergraph conv:  Xp = X@W;  Xe = mean_{v in e} Xp[v];
// Xv[v] = (sum_{e ∋ v} homo[e]*Xe[e]) / (sum_{e ∋ v} homo[e]);  out = rowL2norm(Xp+Xv)
//
// R13 counters: bfv 42.8us @ occ 44% (52.7KB LDS, 391 blocks) -> residency-
// limited gather. R14: quarter buckets (SE_LOG 5, SV_LOG 7), 512-thread
// blocks, CAPB 8192 (~34KB LDS) -> 4 blocks/CU, 782 blocks/side.

#define SE_LOG 5          // edges per bucket = 32
#define SV_LOG 7          // vertices per bucket = 128
#define CH     4096       // incidences per chunk block (both sides)
#define CAPB   8192       // LDS payload capacity (32 KB); avg ~2560, spill else

typedef __attribute__((ext_vector_type(8))) short bf16x8;
typedef __attribute__((ext_vector_type(4))) float f32x4;

__device__ __forceinline__ float bf2f(unsigned short u) {
    union { unsigned int i; float f; } x;
    x.i = ((unsigned int)u) << 16;
    return x.f;
}

__device__ __forceinline__ float bflo(unsigned int u) {
    union { unsigned int i; float f; } x;
    x.i = u << 16;
    return x.f;
}

__device__ __forceinline__ float bfhi(unsigned int u) {
    union { unsigned int i; float f; } x;
    x.i = u & 0xffff0000u;
    return x.f;
}

__device__ __forceinline__ unsigned short f2bf(float f) {
    union { unsigned int i; float ff; } x;
    x.ff = f;
    unsigned int r = x.i + 0x7fff + ((x.i >> 16) & 1);
    return (unsigned short)(r >> 16);
}

__device__ __forceinline__ float loadF(const void* p, size_t i, int bf16mode) {
    return bf16mode ? bf2f(((const unsigned short*)p)[i]) : ((const float*)p)[i];
}

__device__ __forceinline__ int loadI(const void* p, size_t i, int i64mode) {
    return i64mode ? ((const int*)p)[2 * i] : ((const int*)p)[i];
}

// ---------------- dtype sniff: flags[0]=floats-are-bf16, flags[1]=indices-are-i64
__global__ void sniff_kernel(const void* X, const void* vtx, int* flags) {
    if (threadIdx.x != 0 || blockIdx.x != 0) return;
    const unsigned short* u = (const unsigned short*)X;
    int sane = 0;
    for (int i = 0; i < 64; ++i) {
        unsigned short lo = u[2 * i];
        int e = (lo >> 7) & 0xFF;
        if (e >= 110 && e <= 137) ++sane;
    }
    flags[0] = (sane >= 32) ? 1 : 0;
    const int* w = (const int*)vtx;
    int zeros = 0;
    for (int i = 0; i < 64; ++i)
        if (w[2 * i + 1] == 0) ++zeros;
    flags[1] = (zeros >= 32) ? 1 : 0;
}

// ---------------- homo -> f32 -------------------------------------------------
__global__ void homof_kernel(const void* __restrict__ homo,
                             const int* __restrict__ flags,
                             float* __restrict__ homof, int E) {
    int i = blockIdx.x * blockDim.x + threadIdx.x;
    if (i < E) homof[i] = loadF(homo, i, flags[0]);
}

// ---------------- MFMA GEMM (bf16 inputs): Xpb = bf16(X @ W) ------------------
__global__ __launch_bounds__(256)
void gemm_mfma_kernel(const unsigned short* __restrict__ X,
                      const unsigned short* __restrict__ W,
                      const int* __restrict__ flags,
                      unsigned short* __restrict__ Xpb, int N) {
    if (flags[0] == 0) return;
    __shared__ float Ld[4][16 * 68];
    int tid  = threadIdx.x;
    int lane = tid & 63, w = tid >> 6;
    int quad = lane >> 4, c16 = lane & 15;
    bf16x8 bfrag[4][2];
#pragma unroll
    for (int t = 0; t < 4; ++t)
#pragma unroll
        for (int s = 0; s < 2; ++s)
#pragma unroll
            for (int j = 0; j < 8; ++j)
                bfrag[t][s][j] = (short)W[(s * 32 + quad * 8 + j) * 64 + t * 16 + c16];

    int tiles = (N + 15) >> 4;
    int wid = blockIdx.x * 4 + w;
    int nw  = gridDim.x * 4;
    int lr = lane >> 2, seg = lane & 3;
    for (int tile = wid; tile < tiles; tile += nw) {
        int r0 = tile * 16;
        int rA = r0 + c16; if (rA > N - 1) rA = N - 1;
        bf16x8 a0 = *(const bf16x8*)(X + (size_t)rA * 64 + quad * 8);
        bf16x8 a1 = *(const bf16x8*)(X + (size_t)rA * 64 + 32 + quad * 8);
#pragma unroll
        for (int t = 0; t < 4; ++t) {
            f32x4 z = {0.f, 0.f, 0.f, 0.f};
            z = __builtin_amdgcn_mfma_f32_16x16x32_bf16(a0, bfrag[t][0], z, 0, 0, 0);
            z = __builtin_amdgcn_mfma_f32_16x16x32_bf16(a1, bfrag[t][1], z, 0, 0, 0);
#pragma unroll
            for (int i = 0; i < 4; ++i)
                Ld[w][(quad * 4 + i) * 68 + t * 16 + c16] = z[i];
        }
        int r = r0 + lr;
        if (r < N) {
            const float* src = &Ld[w][lr * 68 + seg * 16];
            unsigned int p[8];
#pragma unroll
            for (int i = 0; i < 8; ++i)
                p[i] = (unsigned)f2bf(src[2 * i]) | ((unsigned)f2bf(src[2 * i + 1]) << 16);
            uint4* dst = (uint4*)(Xpb + (size_t)r * 64 + seg * 16);
            dst[0] = make_uint4(p[0], p[1], p[2], p[3]);
            dst[1] = make_uint4(p[4], p[5], p[6], p[7]);
        }
    }
}

// ---------------- VALU GEMM fallback (f32 inputs only) ------------------------
__global__ __launch_bounds__(256)
void gemm_f32_kernel(const void* __restrict__ X, const void* __restrict__ W,
                     const int* __restrict__ flags,
                     unsigned short* __restrict__ Xpb, int N) {
    if (flags[0] == 1) return;
    __shared__ float Ws[64 * 64];
    __shared__ float Xs[16][64];
    int tid = threadIdx.x;
    for (int j = tid; j < 4096; j += 256) Ws[j] = ((const float*)W)[j];
    __syncthreads();
    int lane = tid & 63, w = tid >> 6;
    int wid = (blockIdx.x * 256 + tid) >> 6;
    int nw  = (gridDim.x * 256) >> 6;
    for (int r0 = wid * 4; r0 < N; r0 += nw * 4) {
        if (r0 + 4 <= N) {
            float acc0 = 0.f, acc1 = 0.f, acc2 = 0.f, acc3 = 0.f;
#pragma unroll
            for (int j = 0; j < 4; ++j)
                Xs[w * 4 + j][lane] = ((const float*)X)[(size_t)(r0 + j) * 64 + lane];
#pragma unroll
            for (int k4 = 0; k4 < 16; ++k4) {
                float4 x0 = *(const float4*)&Xs[w * 4 + 0][k4 * 4];
                float4 x1 = *(const float4*)&Xs[w * 4 + 1][k4 * 4];
                float4 x2 = *(const float4*)&Xs[w * 4 + 2][k4 * 4];
                float4 x3 = *(const float4*)&Xs[w * 4 + 3][k4 * 4];
#pragma unroll
                for (int kk = 0; kk < 4; ++kk) {
                    float wv = Ws[(k4 * 4 + kk) * 64 + lane];
                    acc0 = fmaf((&x0.x)[kk], wv, acc0);
                    acc1 = fmaf((&x1.x)[kk], wv, acc1);
                    acc2 = fmaf((&x2.x)[kk], wv, acc2);
                    acc3 = fmaf((&x3.x)[kk], wv, acc3);
                }
            }
            float a[4] = {acc0, acc1, acc2, acc3};
#pragma unroll
            for (int j = 0; j < 4; ++j)
                Xpb[(size_t)(r0 + j) * 64 + lane] = f2bf(a[j]);
        } else {
            for (int r = r0; r < N; ++r) {
                Xs[w * 4][lane] = ((const float*)X)[(size_t)r * 64 + lane];
                float acc = 0.f;
                for (int k = 0; k < 64; ++k)
                    acc = fmaf(Xs[w * 4][k], Ws[k * 64 + lane], acc);
                Xpb[(size_t)r * 64 + lane] = f2bf(acc);
            }
        }
    }
}

// -------- bhist2: both sides per chunk block; one data pass -------------------
__global__ __launch_bounds__(1024)
void bhist2_kernel(const void* __restrict__ edges, const void* __restrict__ vertex,
                   const int* __restrict__ flags, int* __restrict__ btot,
                   int* __restrict__ slabc, int nnz, int NBE, int NBT) {
    __shared__ int cnt[2048];
    int tid = threadIdx.x, b = blockIdx.x;
    for (int j = tid; j < NBT; j += 1024) cnt[j] = 0;
    __syncthreads();
    int imode = flags[1];
    int c0 = b * CH, c1 = min(nnz, c0 + CH);
    for (int i = c0 + tid; i < c1; i += 1024) {
        int e = loadI(edges, i, imode);
        int v = loadI(vertex, i, imode);
        atomicAdd(&cnt[e >> SE_LOG], 1);
        atomicAdd(&cnt[NBE + (v >> SV_LOG)], 1);
    }
    __syncthreads();
    for (int j = tid; j < NBT; j += 1024) {
        int c = cnt[j];
        slabc[(size_t)b * NBT + j] = c;
        if (c) atomicAdd(&btot[j], c);
    }
}

// ---------------- tiny scan over bucket totals -> bases + cursors ------------
__global__ void bscan_kernel(const int* __restrict__ btot, int* __restrict__ bbase,
                             int* __restrict__ bcur, int NBT) {
    __shared__ int wsum[16];
    __shared__ int carry_s;
    int tid = threadIdx.x, lane = tid & 63, w = tid >> 6;
    if (tid == 0) carry_s = 0;
    __syncthreads();
    for (int base = 0; base < NBT; base += 1024) {
        int i = base + tid;
        int x = (i < NBT) ? btot[i] : 0;
        int s = x;
#pragma unroll
        for (int d = 1; d < 64; d <<= 1) {
            int t = __shfl_up(s, d, 64);
            if (lane >= d) s += t;
        }
        if (lane == 63) wsum[w] = s;
        __syncthreads();
        if (w == 0 && lane < 16) {
            int v = wsum[lane];
#pragma unroll
            for (int d = 1; d < 16; d <<= 1) {
                int t = __shfl_up(v, d, 64);
                if (lane >= d) v += t;
            }
            wsum[lane] = v;
        }
        __syncthreads();
        int carry = carry_s;
        int excl  = carry + (w > 0 ? wsum[w - 1] : 0) + s - x;
        if (i < NBT) { bbase[i] = excl; bcur[i] = excl; }
        __syncthreads();
        if (tid == 1023) carry_s = carry + wsum[15];
        __syncthreads();
    }
    if (tid == 0) bbase[NBT] = carry_s;
}

// -------- bscatter2: both sides per chunk block; one data pass ----------------
__global__ __launch_bounds__(1024)
void bscatter2_kernel(const void* __restrict__ edges, const void* __restrict__ vertex,
                      const int* __restrict__ flags, int* __restrict__ bcur,
                      const int* __restrict__ slabc, int* __restrict__ buck,
                      int nnz, int NBE, int NBT, int bitsN, int bitsE) {
    __shared__ int cnt[2048];
    __shared__ int gb[2048];
    int tid = threadIdx.x, b = blockIdx.x;
    for (int j = tid; j < NBT; j += 1024) {
        int c = slabc[(size_t)b * NBT + j];
        gb[j]  = c ? atomicAdd(&bcur[j], c) : 0;
        cnt[j] = 0;
    }
    __syncthreads();
    int imode = flags[1];
    int c0 = b * CH, c1 = min(nnz, c0 + CH);
    for (int i = c0 + tid; i < c1; i += 1024) {
        int e = loadI(edges, i, imode);
        int v = loadI(vertex, i, imode);
        int be = e >> SE_LOG;
        int r  = atomicAdd(&cnt[be], 1);
        buck[gb[be] + r] = ((e & ((1 << SE_LOG) - 1)) << bitsN) | v;
        int bv = NBE + (v >> SV_LOG);
        int r2 = atomicAdd(&cnt[bv], 1);
        buck[gb[bv] + r2] = ((v & ((1 << SV_LOG) - 1)) << bitsE) | e;
    }
}

// -------- bfe: per edge-bucket: LDS sort -> compute Ye rows directly ----------
__global__ __launch_bounds__(512)
void bfe_kernel(const int* __restrict__ buck, const int* __restrict__ bbase,
                const float* __restrict__ homof, int* __restrict__ spill,
                const unsigned short* __restrict__ Xpb,
                unsigned short* __restrict__ Ye, int E, int bitsN) {
    __shared__ int list[CAPB];
    __shared__ int cnt[1 << SE_LOG];
    __shared__ int sexc[1 << SE_LOG];
    __shared__ int wsum[16];
    int g = blockIdx.x;
    int bin0 = g << SE_LOG;
    int nbins = min(1 << SE_LOG, E - bin0);
    int s0 = bbase[g], s1 = bbase[g + 1], size = s1 - s0;
    int tid = threadIdx.x, lane = tid & 63, w = tid >> 6;
    bool sp = (size > CAPB);
    int pmask = (1 << bitsN) - 1;
    if (tid < nbins) cnt[tid] = 0;
    __syncthreads();
    for (int j = tid; j < size; j += 512)
        atomicAdd(&cnt[buck[s0 + j] >> bitsN], 1);
    __syncthreads();
    {   // exclusive scan over nbins (<= 32 -> single wave)
        int x = (tid < nbins) ? cnt[tid] : 0;
        int s = x;
#pragma unroll
        for (int d = 1; d < 64; d <<= 1) {
            int t = __shfl_up(s, d, 64);
            if (lane >= d) s += t;
        }
        if (w == 0 && tid < nbins) sexc[tid] = s - x;
    }
    __syncthreads();
    if (tid < nbins) cnt[tid] = sexc[tid];   // cursors
    __syncthreads();
    for (int j = tid; j < size; j += 512) {
        int p  = buck[s0 + j];
        int lb = p >> bitsN;
        int r  = atomicAdd(&cnt[lb], 1);
        int v  = p & pmask;
        if (sp) spill[s0 + r] = v; else list[r] = v;
    }
    __syncthreads();
    // compute: 32 groups x 16 lanes; group owns one edge; lane owns 4 channels
    int grp = tid >> 4;
    int c = tid & 15;
    unsigned co = (unsigned)c << 3;
    if (grp < nbins) {
        int start = sexc[grp], end = cnt[grp];   // cursor == segment end
        const char* Xb = (const char*)Xpb;
        float a0 = 0.f, a1 = 0.f, a2 = 0.f, a3 = 0.f;
        int j = start;
        if (!sp) {
            for (; j + 3 < end; j += 4) {
                int v0 = list[j], v1 = list[j + 1], v2 = list[j + 2], v3 = list[j + 3];
                uint2 u0 = *(const uint2*)(Xb + (((unsigned)v0 << 7) + co));
                uint2 u1 = *(const uint2*)(Xb + (((unsigned)v1 << 7) + co));
                uint2 u2 = *(const uint2*)(Xb + (((unsigned)v2 << 7) + co));
                uint2 u3 = *(const uint2*)(Xb + (((unsigned)v3 << 7) + co));
                a0 += (bflo(u0.x) + bflo(u1.x)) + (bflo(u2.x) + bflo(u3.x));
                a1 += (bfhi(u0.x) + bfhi(u1.x)) + (bfhi(u2.x) + bfhi(u3.x));
                a2 += (bflo(u0.y) + bflo(u1.y)) + (bflo(u2.y) + bflo(u3.y));
                a3 += (bfhi(u0.y) + bfhi(u1.y)) + (bfhi(u2.y) + bfhi(u3.y));
            }
            for (; j < end; ++j) {
                int v = list[j];
                uint2 u = *(const uint2*)(Xb + (((unsigned)v << 7) + co));
                a0 += bflo(u.x); a1 += bfhi(u.x);
                a2 += bflo(u.y); a3 += bfhi(u.y);
            }
        } else {
            for (; j < end; ++j) {
                int v = spill[s0 + j];
                uint2 u = *(const uint2*)(Xb + (((unsigned)v << 7) + co));
                a0 += bflo(u.x); a1 += bfhi(u.x);
                a2 += bflo(u.y); a3 += bfhi(u.y);
            }
        }
        int e = bin0 + grp;
        float inv = homof[e] / fmaxf((float)(end - start), 1.f);
        unsigned p0 = (unsigned)f2bf(a0 * inv) | ((unsigned)f2bf(a1 * inv) << 16);
        unsigned p1 = (unsigned)f2bf(a2 * inv) | ((unsigned)f2bf(a3 * inv) << 16);
        *(uint2*)((char*)Ye + (((unsigned)e << 7) + co)) = make_uint2(p0, p1);
    }
}

// -------- bfv: per vertex-bucket: LDS sort -> final output rows ---------------
__global__ __launch_bounds__(512)
void bfv_kernel(const int* __restrict__ buck, const int* __restrict__ bbase,
                const float* __restrict__ homof, int* __restrict__ spill,
                const unsigned short* __restrict__ Xpb,
                const unsigned short* __restrict__ Ye,
                float* __restrict__ out, int N, int NBE, int bitsE) {
    __shared__ int list[CAPB];
    __shared__ int cnt[1 << SV_LOG];
    __shared__ int sexc[1 << SV_LOG];
    __shared__ float hsum[1 << SV_LOG];
    __shared__ int wsum[16];
    int bv = blockIdx.x;
    int bin0 = bv << SV_LOG;
    int nbins = min(1 << SV_LOG, N - bin0);
    int s0 = bbase[NBE + bv], s1 = bbase[NBE + bv + 1], size = s1 - s0;
    int tid = threadIdx.x, lane = tid & 63, w = tid >> 6;
    bool sp = (size > CAPB);
    int pmask = (1 << bitsE) - 1;
    if (tid < nbins) { cnt[tid] = 0; hsum[tid] = 0.f; }
    __syncthreads();
    for (int j = tid; j < size; j += 512)
        atomicAdd(&cnt[buck[s0 + j] >> bitsE], 1);
    __syncthreads();
    {   // exclusive scan over nbins (<= 128 -> 2 waves)
        int x = (tid < nbins) ? cnt[tid] : 0;
        int s = x;
#pragma unroll
        for (int d = 1; d < 64; d <<= 1) {
            int t = __shfl_up(s, d, 64);
            if (lane >= d) s += t;
        }
        if (lane == 63) wsum[w] = s;
        __syncthreads();
        if (w == 0 && lane < 16) {
            int v = wsum[lane];
#pragma unroll
            for (int d = 1; d < 16; d <<= 1) {
                int t = __shfl_up(v, d, 64);
                if (lane >= d) v += t;
            }
            wsum[lane] = v;
        }
        __syncthreads();
        int excl = s - x + (w > 0 ? wsum[w - 1] : 0);
        if (tid < nbins) sexc[tid] = excl;
    }
    __syncthreads();
    if (tid < nbins) cnt[tid] = sexc[tid];
    __syncthreads();
    for (int j = tid; j < size; j += 512) {
        int p  = buck[s0 + j];
        int lb = p >> bitsE;
        int r  = atomicAdd(&cnt[lb], 1);
        int e  = p & pmask;
        if (sp) spill[s0 + r] = e; else list[r] = e;
        atomicAdd(&hsum[lb], homof[e]);
    }
    __syncthreads();
    // compute: 64 groups x 8 lanes; group owns vertices grp, grp+64
    int grp = tid >> 3;
    int c = tid & 7;
    unsigned co = (unsigned)c << 4;
    const char* Yb = (const char*)Ye;
    for (int vl = grp; vl < nbins; vl += 64) {
        int start = sexc[vl], end = cnt[vl];
        float a0 = 0.f, a1 = 0.f, a2 = 0.f, a3 = 0.f;
        float a4 = 0.f, a5 = 0.f, a6 = 0.f, a7 = 0.f;
        int j = start;
        if (!sp) {
            for (; j + 3 < end; j += 4) {
                int e0 = list[j], e1 = list[j + 1], e2 = list[j + 2], e3 = list[j + 3];
                uint4 u0 = *(const uint4*)(Yb + (((unsigned)e0 << 7) + co));
                uint4 u1 = *(const uint4*)(Yb + (((unsigned)e1 << 7) + co));
                uint4 u2 = *(const uint4*)(Yb + (((unsigned)e2 << 7) + co));
                uint4 u3 = *(const uint4*)(Yb + (((unsigned)e3 << 7) + co));
                a0 += (bflo(u0.x) + bflo(u1.x)) + (bflo(u2.x) + bflo(u3.x));
                a1 += (bfhi(u0.x) + bfhi(u1.x)) + (bfhi(u2.x) + bfhi(u3.x));
                a2 += (bflo(u0.y) + bflo(u1.y)) + (bflo(u2.y) + bflo(u3.y));
                a3 += (bfhi(u0.y) + bfhi(u1.y)) + (bfhi(u2.y) + bfhi(u3.y));
                a4 += (bflo(u0.z) + bflo(u1.z)) + (bflo(u2.z) + bflo(u3.z));
                a5 += (bfhi(u0.z) + bfhi(u1.z)) + (bfhi(u2.z) + bfhi(u3.z));
                a6 += (bflo(u0.w) + bflo(u1.w)) + (bflo(u2.w) + bflo(u3.w));
                a7 += (bfhi(u0.w) + bfhi(u1.w)) + (bfhi(u2.w) + bfhi(u3.w));
            }
            for (; j < end; ++j) {
                int e = list[j];
                uint4 u = *(const uint4*)(Yb + (((unsigned)e << 7) + co));
                a0 += bflo(u.x); a1 += bfhi(u.x);
                a2 += bflo(u.y); a3 += bfhi(u.y);
                a4 += bflo(u.z); a5 += bfhi(u.z);
                a6 += bflo(u.w); a7 += bfhi(u.w);
            }
        } else {
            for (; j < end; ++j) {
                int e = spill[s0 + j];
                uint4 u = *(const uint4*)(Yb + (((unsigned)e << 7) + co));
                a0 += bflo(u.x); a1 += bfhi(u.x);
                a2 += bflo(u.y); a3 += bfhi(u.y);
                a4 += bflo(u.z); a5 += bfhi(u.z);
                a6 += bflo(u.w); a7 += bfhi(u.w);
            }
        }
        int vid = bin0 + vl;
        float hsv = hsum[vl];
        float inv = (hsv > 0.f) ? 1.f / hsv : 0.f;
        uint4 xu = *(const uint4*)((const char*)Xpb + (((unsigned)vid << 7) + co));
        float r0 = bflo(xu.x) + a0 * inv, r1 = bfhi(xu.x) + a1 * inv;
        float r2 = bflo(xu.y) + a2 * inv, r3 = bfhi(xu.y) + a3 * inv;
        float r4 = bflo(xu.z) + a4 * inv, r5 = bfhi(xu.z) + a5 * inv;
        float r6 = bflo(xu.w) + a6 * inv, r7 = bfhi(xu.w) + a7 * inv;
        float ss = ((r0 * r0 + r1 * r1) + (r2 * r2 + r3 * r3)) +
                   ((r4 * r4 + r5 * r5) + (r6 * r6 + r7 * r7));
        ss += __shfl_xor(ss, 1, 64);
        ss += __shfl_xor(ss, 2, 64);
        ss += __shfl_xor(ss, 4, 64);
        float rn    = sqrtf(ss);
        float scale = (rn > 0.f) ? 1.f / fmaxf(rn, 1e-30f) : 0.f;
        char* ob = (char*)out + (((unsigned)vid << 8) + (co << 1));
        *(float4*)ob        = make_float4(r0 * scale, r1 * scale, r2 * scale, r3 * scale);
        *(float4*)(ob + 16) = make_float4(r4 * scale, r5 * scale, r6 * scale, r7 * scale);
    }
}

// ================= fallback path (old, verified kernels) =====================
__global__ void hist_atomic_kernel(const void* __restrict__ edges,
                                   const void* __restrict__ vertex,
                                   const int* __restrict__ flags,
                                   int* __restrict__ tot, int E, int nnz) {
    int i = blockIdx.x * blockDim.x + threadIdx.x;
    if (i >= nnz) return;
    int imode = flags[1];
    atomicAdd(&tot[loadI(edges, i, imode)], 1);
    atomicAdd(&tot[E + loadI(vertex, i, imode)], 1);
}

__global__ void scan_part_kernel(const int* __restrict__ tot, int* __restrict__ part, int M) {
    int g = blockIdx.x, tid = threadIdx.x;
    int base = g * 2048;
    int sum = 0;
    for (int j = tid; j < 2048; j += 256) {
        int i = base + j;
        sum += (i < M) ? tot[i] : 0;
    }
#pragma unroll
    for (int d = 32; d >= 1; d >>= 1) sum += __shfl_xor(sum, d, 64);
    __shared__ int wsums[4];
    int lane = tid & 63, w = tid >> 6;
    if (lane == 0) wsums[w] = sum;
    __syncthreads();
    if (tid == 0) part[g] = wsums[0] + wsums[1] + wsums[2] + wsums[3];
}

__global__ void scan_root_kernel(int* __restrict__ part, int G,
                                 int* __restrict__ off, int M) {
    int tid = threadIdx.x, lane = tid & 63, w = tid >> 6;
    int x = (tid < G) ? part[tid] : 0;
    int s = x;
#pragma unroll
    for (int d = 1; d < 64; d <<= 1) {
        int t = __shfl_up(s, d, 64);
        if (lane >= d) s += t;
    }
    __shared__ int ws[16];
    if (lane == 63) ws[w] = s;
    __syncthreads();
    if (w == 0 && lane < 16) {
        int v = ws[lane];
#pragma unroll
        for (int d = 1; d < 16; d <<= 1) {
            int t = __shfl_up(v, d, 64);
            if (lane >= d) v += t;
        }
        ws[lane] = v;
    }
    __syncthreads();
    int excl = s - x + (w > 0 ? ws[w - 1] : 0);
    if (tid < G) part[tid] = excl;
    if (tid == 1023) off[M] = ws[15];
}

__global__ void scan_apply_kernel(int* __restrict__ tot, const int* __restrict__ part,
                                  int* __restrict__ off, int M) {
    int g = blockIdx.x, tid = threadIdx.x, lane = tid & 63, w = tid >> 6;
    int base = g * 2048 + tid * 8;
    int e[8]; int s = 0;
#pragma unroll
    for (int j = 0; j < 8; ++j) {
        int i = base + j;
        e[j] = (i < M) ? tot[i] : 0;
        s += e[j];
    }
    int si = s;
#pragma unroll
    for (int d = 1; d < 64; d <<= 1) {
        int t = __shfl_up(si, d, 64);
        if (lane >= d) si += t;
    }
    __shared__ int wsum[4];
    if (lane == 63) wsum[w] = si;
    __syncthreads();
    int wbase = 0;
    for (int ww = 0; ww < w; ++ww) wbase += wsum[ww];
    int run = part[g] + wbase + si - s;
#pragma unroll
    for (int j = 0; j < 8; ++j) {
        int i = base + j;
        if (i < M) off[i] = run;
        run += e[j];
    }
}

__global__ void copy_kernel(const int* __restrict__ src, int* __restrict__ dst, int n) {
    int i = blockIdx.x * blockDim.x + threadIdx.x;
    if (i < n) dst[i] = src[i];
}

__global__ void scatter_atomic_kernel(const void* __restrict__ edges,
                                      const void* __restrict__ vertex,
                                      const int* __restrict__ flags,
                                      int* __restrict__ cur, int* __restrict__ dest,
                                      int E, int nnz) {
    int i = blockIdx.x * blockDim.x + threadIdx.x;
    if (i >= nnz) return;
    int imode = flags[1];
    int e = loadI(edges, i, imode);
    int v = loadI(vertex, i, imode);
    dest[atomicAdd(&cur[e], 1)]     = v;
    dest[atomicAdd(&cur[E + v], 1)] = e;
}

__global__ void hs_fallback_kernel(const int* __restrict__ off,
                                   const int* __restrict__ sorted,
                                   const float* __restrict__ homof,
                                   float* __restrict__ hs, int E, int N) {
    int v = blockIdx.x * blockDim.x + threadIdx.x;
    if (v >= N) return;
    int s = off[E + v], e = off[E + v + 1];
    float t = 0.f;
    for (int j = s; j < e; ++j) t += homof[sorted[j]];
    hs[v] = t;
}

__global__ void edge_mean_kernel(const unsigned short* __restrict__ Xpb,
                                 const int* __restrict__ off,
                                 const int* __restrict__ sorted,
                                 const float* __restrict__ homof,
                                 unsigned short* __restrict__ Ye, int E) {
    int wid  = (blockIdx.x * blockDim.x + threadIdx.x) >> 6;
    int lane = threadIdx.x & 63;
    if (wid >= E) return;
    int g = lane >> 4, c = lane & 15;
    unsigned co = (unsigned)c << 3;
    int start = off[wid], end = off[wid + 1];
    float a0 = 0.f, a1 = 0.f, a2 = 0.f, a3 = 0.f;
    const char* Xb = (const char*)Xpb;
    for (int j = start + g; j < end; j += 4) {
        int v = sorted[j];
        uint2 u = *(const uint2*)(Xb + (((unsigned)v << 7) + co));
        a0 += bflo(u.x); a1 += bfhi(u.x);
        a2 += bflo(u.y); a3 += bfhi(u.y);
    }
    a0 += __shfl_xor(a0, 16, 64); a0 += __shfl_xor(a0, 32, 64);
    a1 += __shfl_xor(a1, 16, 64); a1 += __shfl_xor(a1, 32, 64);
    a2 += __shfl_xor(a2, 16, 64); a2 += __shfl_xor(a2, 32, 64);
    a3 += __shfl_xor(a3, 16, 64); a3 += __shfl_xor(a3, 32, 64);
    if (g == 0) {
        float inv = homof[wid] / fmaxf((float)(end - start), 1.f);
        unsigned p0 = (unsigned)f2bf(a0 * inv) | ((unsigned)f2bf(a1 * inv) << 16);
        unsigned p1 = (unsigned)f2bf(a2 * inv) | ((unsigned)f2bf(a3 * inv) << 16);
        *(uint2*)((char*)Ye + (((unsigned)wid << 7) + co)) = make_uint2(p0, p1);
    }
}

__global__ void vertex_out_kernel(const unsigned short* __restrict__ Xpb,
                                  const unsigned short* __restrict__ Ye,
                                  const int* __restrict__ off,
                                  const int* __restrict__ sorted,
                                  const float* __restrict__ hs,
                                  float* __restrict__ out, int E, int N) {
    int wv   = (blockIdx.x * blockDim.x + threadIdx.x) >> 6;
    int lane = threadIdx.x & 63;
    int g = lane >> 3, c = lane & 7;
    int vid = wv * 8 + g;
    if (vid >= N) return;
    unsigned co = (unsigned)c << 4;
    int start = off[E + vid], end = off[E + vid + 1];
    float a0 = 0.f, a1 = 0.f, a2 = 0.f, a3 = 0.f;
    float a4 = 0.f, a5 = 0.f, a6 = 0.f, a7 = 0.f;
    const char* Yb = (const char*)Ye;
    for (int j = start; j < end; ++j) {
        int e = sorted[j];
        uint4 u = *(const uint4*)(Yb + (((unsigned)e << 7) + co));
        a0 += bflo(u.x); a1 += bfhi(u.x);
        a2 += bflo(u.y); a3 += bfhi(u.y);
        a4 += bflo(u.z); a5 += bfhi(u.z);
        a6 += bflo(u.w); a7 += bfhi(u.w);
    }
    float hsv = hs[vid];
    float inv = (hsv > 0.f) ? 1.f / hsv : 0.f;
    uint4 xu = *(const uint4*)((const char*)Xpb + (((unsigned)vid << 7) + co));
    float r0 = bflo(xu.x) + a0 * inv, r1 = bfhi(xu.x) + a1 * inv;
    float r2 = bflo(xu.y) + a2 * inv, r3 = bfhi(xu.y) + a3 * inv;
    float r4 = bflo(xu.z) + a4 * inv, r5 = bfhi(xu.z) + a5 * inv;
    float r6 = bflo(xu.w) + a6 * inv, r7 = bfhi(xu.w) + a7 * inv;
    float ss = ((r0 * r0 + r1 * r1) + (r2 * r2 + r3 * r3)) +
               ((r4 * r4 + r5 * r5) + (r6 * r6 + r7 * r7));
    ss += __shfl_xor(ss, 1, 64);
    ss += __shfl_xor(ss, 2, 64);
    ss += __shfl_xor(ss, 4, 64);
    float rn    = sqrtf(ss);
    float scale = (rn > 0.f) ? 1.f / fmaxf(rn, 1e-30f) : 0.f;
    char* ob = (char*)out + (((unsigned)vid << 8) + (co << 1));
    *(float4*)ob        = make_float4(r0 * scale, r1 * scale, r2 * scale, r3 * scale);
    *(float4*)(ob + 16) = make_float4(r4 * scale, r5 * scale, r6 * scale, r7 * scale);
}

static inline int ceil_bits(int n) {
    int v = n - 1;
    if (v < 1) v = 1;
    int b = 0;
    while ((1 << b) <= v) ++b;
    return b;
}

extern "C" void kernel_launch(void* const* d_in, const int* in_sizes, int n_in,
                              void* d_out, int out_size, void* d_ws, size_t ws_size,
                              hipStream_t stream) {
    const void* X      = d_in[0];
    const void* W      = d_in[1];
    const void* homo   = d_in[2];
    const void* vertex = d_in[3];
    const void* edges  = d_in[4];
    float* out = (float*)d_out;

    const int N   = in_sizes[0] / 64;
    const int E   = in_sizes[2];
    const int NNZ = in_sizes[3];
    const int M   = E + N;

    const int NBE = (E + (1 << SE_LOG) - 1) >> SE_LOG;
    const int NBV = (N + (1 << SV_LOG) - 1) >> SV_LOG;
    const int NBT = NBE + NBV;
    const int GC  = (NNZ + CH - 1) / CH;
    const int bitsN = ceil_bits(N);
    const int bitsE = ceil_bits(E);
    const int G   = (M + 2047) / 2048;  // fallback scan tiles

    char*  ws = (char*)d_ws;
    size_t o  = 0;
    auto alloc = [&](size_t bytes) -> void* {
        void* p = ws + o;
        o += (bytes + 255) & ~(size_t)255;
        return p;
    };
    int*            flags = (int*)alloc(2 * 4);
    int*            bbase = (int*)alloc((size_t)(NBT + 1) * 4);
    int*            bcur  = (int*)alloc((size_t)NBT * 4);
    int*            btot  = (int*)alloc((size_t)NBT * 4);
    float*          homof = (float*)alloc((size_t)E * 4);
    int*            buck  = (int*)alloc((size_t)2 * NNZ * 4);
    int*            spill = (int*)alloc((size_t)2 * NNZ * 4);  // fallback: sorted
    unsigned short* Xpb   = (unsigned short*)alloc((size_t)N * 64 * 2);
    unsigned short* Ye    = (unsigned short*)alloc((size_t)E * 64 * 2);
    int*            slabc = (int*)alloc((size_t)GC * NBT * 4);
    size_t o_common = o;
    bool fast = (o <= ws_size) && NBT <= 2048 &&
                (SE_LOG + bitsN <= 31) && (SV_LOG + bitsE <= 31) && G <= 1024;
    (void)n_in; (void)out_size;

    sniff_kernel<<<1, 64, 0, stream>>>(X, vertex, flags);
    homof_kernel<<<(E + 255) / 256, 256, 0, stream>>>(homo, flags, homof, E);
    gemm_mfma_kernel<<<1024, 256, 0, stream>>>((const unsigned short*)X,
                                               (const unsigned short*)W,
                                               flags, Xpb, N);
    gemm_f32_kernel<<<512, 256, 0, stream>>>(X, W, flags, Xpb, N);

    if (fast) {
        hipMemsetAsync(btot, 0, (size_t)NBT * 4, stream);
        bhist2_kernel<<<GC, 1024, 0, stream>>>(edges, vertex, flags, btot,
                                               slabc, NNZ, NBE, NBT);
        bscan_kernel<<<1, 1024, 0, stream>>>(btot, bbase, bcur, NBT);
        bscatter2_kernel<<<GC, 1024, 0, stream>>>(edges, vertex, flags, bcur,
                                                  slabc, buck, NNZ, NBE, NBT,
                                                  bitsN, bitsE);
        bfe_kernel<<<NBE, 512, 0, stream>>>(buck, bbase, homof, spill,
                                            Xpb, Ye, E, bitsN);
        bfv_kernel<<<NBV, 512, 0, stream>>>(buck, bbase, homof, spill,
                                            Xpb, Ye, out, N, NBE, bitsE);
    } else {
        o = o_common;
        int* off  = (int*)alloc((size_t)(M + 1) * 4);
        float* hs = (float*)alloc((size_t)N * 4);
        int* tot  = (int*)alloc((size_t)M * 4);
        int* part = (int*)alloc((size_t)(G + 1) * 4);
        int* cur  = (int*)alloc((size_t)M * 4);
        int* sorted = spill;
        hipMemsetAsync(tot, 0, (size_t)M * 4, stream);
        int nb = (NNZ + 255) / 256;
        hist_atomic_kernel<<<nb, 256, 0, stream>>>(edges, vertex, flags, tot, E, NNZ);
        scan_part_kernel<<<G, 256, 0, stream>>>(tot, part, M);
        scan_root_kernel<<<1, 1024, 0, stream>>>(part, G, off, M);
        scan_apply_kernel<<<G, 256, 0, stream>>>(tot, part, off, M);
        copy_kernel<<<(M + 255) / 256, 256, 0, stream>>>(off, cur, M);
        scatter_atomic_kernel<<<nb, 256, 0, stream>>>(edges, vertex, flags, cur, sorted, E, NNZ);
        hs_fallback_kernel<<<(N + 255) / 256, 256, 0, stream>>>(off, sorted, homof, hs, E, N);
        edge_mean_kernel<<<(E + 3) / 4, 256, 0, stream>>>(Xpb, off, sorted, homof, Ye, E);
        int vwaves  = (N + 7) / 8;
        int vblocks = (vwaves * 64 + 255) / 256;
        vertex_out_kernel<<<vblocks, 256, 0, stream>>>(Xpb, Ye, off, sorted, hs, out, E, N);
    }
}

// Round 15
// 259.420 us; speedup vs baseline: 1.0101x; 1.0101x over previous
//
#include <hip/hip_runtime.h>
#include <hip/hip_bf16.h>

// Hypergraph conv:  Xp = X@W;  Xe = mean_{v in e} Xp[v];
// Xv[v] = (sum_{e ∋ v} homo[e]*Xe[e]) / (sum_{e ∋ v} homo[e]);  out = rowL2norm(Xp+Xv)
//
// R14 lesson: small buckets re-introduced scatter line-bouncing (WRITE 107MB).
// R15: sort geometry reverted to R13 (64-edge/256-vertex buckets, ~10-int
// runs); bfe/bfv occupancy fixed orthogonally — 2 blocks per bucket, each
// 512 threads handling HALF the bucket's bins (~34KB LDS -> 4 blocks/CU,
// 782 blocks/side). Halves' spill regions are disjoint by construction.

#define SE_LOG 6          // edges per bucket = 64
#define SV_LOG 8          // vertices per bucket = 256
#define CH     4096       // incidences per chunk block (both sides)
#define CAPB   8192       // LDS payload capacity per half (32 KB)

typedef __attribute__((ext_vector_type(8))) short bf16x8;
typedef __attribute__((ext_vector_type(4))) float f32x4;

__device__ __forceinline__ float bf2f(unsigned short u) {
    union { unsigned int i; float f; } x;
    x.i = ((unsigned int)u) << 16;
    return x.f;
}

__device__ __forceinline__ float bflo(unsigned int u) {
    union { unsigned int i; float f; } x;
    x.i = u << 16;
    return x.f;
}

__device__ __forceinline__ float bfhi(unsigned int u) {
    union { unsigned int i; float f; } x;
    x.i = u & 0xffff0000u;
    return x.f;
}

__device__ __forceinline__ unsigned short f2bf(float f) {
    union { unsigned int i; float ff; } x;
    x.ff = f;
    unsigned int r = x.i + 0x7fff + ((x.i >> 16) & 1);
    return (unsigned short)(r >> 16);
}

__device__ __forceinline__ float loadF(const void* p, size_t i, int bf16mode) {
    return bf16mode ? bf2f(((const unsigned short*)p)[i]) : ((const float*)p)[i];
}

__device__ __forceinline__ int loadI(const void* p, size_t i, int i64mode) {
    return i64mode ? ((const int*)p)[2 * i] : ((const int*)p)[i];
}

// ---------------- dtype sniff: flags[0]=floats-are-bf16, flags[1]=indices-are-i64
__global__ void sniff_kernel(const void* X, const void* vtx, int* flags) {
    if (threadIdx.x != 0 || blockIdx.x != 0) return;
    const unsigned short* u = (const unsigned short*)X;
    int sane = 0;
    for (int i = 0; i < 64; ++i) {
        unsigned short lo = u[2 * i];
        int e = (lo >> 7) & 0xFF;
        if (e >= 110 && e <= 137) ++sane;
    }
    flags[0] = (sane >= 32) ? 1 : 0;
    const int* w = (const int*)vtx;
    int zeros = 0;
    for (int i = 0; i < 64; ++i)
        if (w[2 * i + 1] == 0) ++zeros;
    flags[1] = (zeros >= 32) ? 1 : 0;
}

// ---------------- homo -> f32 -------------------------------------------------
__global__ void homof_kernel(const void* __restrict__ homo,
                             const int* __restrict__ flags,
                             float* __restrict__ homof, int E) {
    int i = blockIdx.x * blockDim.x + threadIdx.x;
    if (i < E) homof[i] = loadF(homo, i, flags[0]);
}

// ---------------- MFMA GEMM (bf16 inputs): Xpb = bf16(X @ W) ------------------
__global__ __launch_bounds__(256)
void gemm_mfma_kernel(const unsigned short* __restrict__ X,
                      const unsigned short* __restrict__ W,
                      const int* __restrict__ flags,
                      unsigned short* __restrict__ Xpb, int N) {
    if (flags[0] == 0) return;
    __shared__ float Ld[4][16 * 68];
    int tid  = threadIdx.x;
    int lane = tid & 63, w = tid >> 6;
    int quad = lane >> 4, c16 = lane & 15;
    bf16x8 bfrag[4][2];
#pragma unroll
    for (int t = 0; t < 4; ++t)
#pragma unroll
        for (int s = 0; s < 2; ++s)
#pragma unroll
            for (int j = 0; j < 8; ++j)
                bfrag[t][s][j] = (short)W[(s * 32 + quad * 8 + j) * 64 + t * 16 + c16];

    int tiles = (N + 15) >> 4;
    int wid = blockIdx.x * 4 + w;
    int nw  = gridDim.x * 4;
    int lr = lane >> 2, seg = lane & 3;
    for (int tile = wid; tile < tiles; tile += nw) {
        int r0 = tile * 16;
        int rA = r0 + c16; if (rA > N - 1) rA = N - 1;
        bf16x8 a0 = *(const bf16x8*)(X + (size_t)rA * 64 + quad * 8);
        bf16x8 a1 = *(const bf16x8*)(X + (size_t)rA * 64 + 32 + quad * 8);
#pragma unroll
        for (int t = 0; t < 4; ++t) {
            f32x4 z = {0.f, 0.f, 0.f, 0.f};
            z = __builtin_amdgcn_mfma_f32_16x16x32_bf16(a0, bfrag[t][0], z, 0, 0, 0);
            z = __builtin_amdgcn_mfma_f32_16x16x32_bf16(a1, bfrag[t][1], z, 0, 0, 0);
#pragma unroll
            for (int i = 0; i < 4; ++i)
                Ld[w][(quad * 4 + i) * 68 + t * 16 + c16] = z[i];
        }
        int r = r0 + lr;
        if (r < N) {
            const float* src = &Ld[w][lr * 68 + seg * 16];
            unsigned int p[8];
#pragma unroll
            for (int i = 0; i < 8; ++i)
                p[i] = (unsigned)f2bf(src[2 * i]) | ((unsigned)f2bf(src[2 * i + 1]) << 16);
            uint4* dst = (uint4*)(Xpb + (size_t)r * 64 + seg * 16);
            dst[0] = make_uint4(p[0], p[1], p[2], p[3]);
            dst[1] = make_uint4(p[4], p[5], p[6], p[7]);
        }
    }
}

// ---------------- VALU GEMM fallback (f32 inputs only) ------------------------
__global__ __launch_bounds__(256)
void gemm_f32_kernel(const void* __restrict__ X, const void* __restrict__ W,
                     const int* __restrict__ flags,
                     unsigned short* __restrict__ Xpb, int N) {
    if (flags[0] == 1) return;
    __shared__ float Ws[64 * 64];
    __shared__ float Xs[16][64];
    int tid = threadIdx.x;
    for (int j = tid; j < 4096; j += 256) Ws[j] = ((const float*)X == nullptr) ? 0.f : ((const float*)W)[j];
    __syncthreads();
    int lane = tid & 63, w = tid >> 6;
    int wid = (blockIdx.x * 256 + tid) >> 6;
    int nw  = (gridDim.x * 256) >> 6;
    for (int r0 = wid * 4; r0 < N; r0 += nw * 4) {
        if (r0 + 4 <= N) {
            float acc0 = 0.f, acc1 = 0.f, acc2 = 0.f, acc3 = 0.f;
#pragma unroll
            for (int j = 0; j < 4; ++j)
                Xs[w * 4 + j][lane] = ((const float*)X)[(size_t)(r0 + j) * 64 + lane];
#pragma unroll
            for (int k4 = 0; k4 < 16; ++k4) {
                float4 x0 = *(const float4*)&Xs[w * 4 + 0][k4 * 4];
                float4 x1 = *(const float4*)&Xs[w * 4 + 1][k4 * 4];
                float4 x2 = *(const float4*)&Xs[w * 4 + 2][k4 * 4];
                float4 x3 = *(const float4*)&Xs[w * 4 + 3][k4 * 4];
#pragma unroll
                for (int kk = 0; kk < 4; ++kk) {
                    float wv = Ws[(k4 * 4 + kk) * 64 + lane];
                    acc0 = fmaf((&x0.x)[kk], wv, acc0);
                    acc1 = fmaf((&x1.x)[kk], wv, acc1);
                    acc2 = fmaf((&x2.x)[kk], wv, acc2);
                    acc3 = fmaf((&x3.x)[kk], wv, acc3);
                }
            }
            float a[4] = {acc0, acc1, acc2, acc3};
#pragma unroll
            for (int j = 0; j < 4; ++j)
                Xpb[(size_t)(r0 + j) * 64 + lane] = f2bf(a[j]);
        } else {
            for (int r = r0; r < N; ++r) {
                Xs[w * 4][lane] = ((const float*)X)[(size_t)r * 64 + lane];
                float acc = 0.f;
                for (int k = 0; k < 64; ++k)
                    acc = fmaf(Xs[w * 4][k], Ws[k * 64 + lane], acc);
                Xpb[(size_t)r * 64 + lane] = f2bf(acc);
            }
        }
    }
}

// -------- bhist2: both sides per chunk block; one data pass -------------------
__global__ __launch_bounds__(1024)
void bhist2_kernel(const void* __restrict__ edges, const void* __restrict__ vertex,
                   const int* __restrict__ flags, int* __restrict__ btot,
                   int* __restrict__ slabc, int nnz, int NBE, int NBT) {
    __shared__ int cnt[2048];
    int tid = threadIdx.x, b = blockIdx.x;
    for (int j = tid; j < NBT; j += 1024) cnt[j] = 0;
    __syncthreads();
    int imode = flags[1];
    int c0 = b * CH, c1 = min(nnz, c0 + CH);
    for (int i = c0 + tid; i < c1; i += 1024) {
        int e = loadI(edges, i, imode);
        int v = loadI(vertex, i, imode);
        atomicAdd(&cnt[e >> SE_LOG], 1);
        atomicAdd(&cnt[NBE + (v >> SV_LOG)], 1);
    }
    __syncthreads();
    for (int j = tid; j < NBT; j += 1024) {
        int c = cnt[j];
        slabc[(size_t)b * NBT + j] = c;
        if (c) atomicAdd(&btot[j], c);
    }
}

// ---------------- tiny scan over bucket totals -> bases + cursors ------------
__global__ void bscan_kernel(const int* __restrict__ btot, int* __restrict__ bbase,
                             int* __restrict__ bcur, int NBT) {
    __shared__ int wsum[16];
    __shared__ int carry_s;
    int tid = threadIdx.x, lane = tid & 63, w = tid >> 6;
    if (tid == 0) carry_s = 0;
    __syncthreads();
    for (int base = 0; base < NBT; base += 1024) {
        int i = base + tid;
        int x = (i < NBT) ? btot[i] : 0;
        int s = x;
#pragma unroll
        for (int d = 1; d < 64; d <<= 1) {
            int t = __shfl_up(s, d, 64);
            if (lane >= d) s += t;
        }
        if (lane == 63) wsum[w] = s;
        __syncthreads();
        if (w == 0 && lane < 16) {
            int v = wsum[lane];
#pragma unroll
            for (int d = 1; d < 16; d <<= 1) {
                int t = __shfl_up(v, d, 64);
                if (lane >= d) v += t;
            }
            wsum[lane] = v;
        }
        __syncthreads();
        int carry = carry_s;
        int excl  = carry + (w > 0 ? wsum[w - 1] : 0) + s - x;
        if (i < NBT) { bbase[i] = excl; bcur[i] = excl; }
        __syncthreads();
        if (tid == 1023) carry_s = carry + wsum[15];
        __syncthreads();
    }
    if (tid == 0) bbase[NBT] = carry_s;
}

// -------- bscatter2: both sides per chunk block; one data pass ----------------
__global__ __launch_bounds__(1024)
void bscatter2_kernel(const void* __restrict__ edges, const void* __restrict__ vertex,
                      const int* __restrict__ flags, int* __restrict__ bcur,
                      const int* __restrict__ slabc, int* __restrict__ buck,
                      int nnz, int NBE, int NBT, int bitsN, int bitsE) {
    __shared__ int cnt[2048];
    __shared__ int gb[2048];
    int tid = threadIdx.x, b = blockIdx.x;
    for (int j = tid; j < NBT; j += 1024) {
        int c = slabc[(size_t)b * NBT + j];
        gb[j]  = c ? atomicAdd(&bcur[j], c) : 0;
        cnt[j] = 0;
    }
    __syncthreads();
    int imode = flags[1];
    int c0 = b * CH, c1 = min(nnz, c0 + CH);
    for (int i = c0 + tid; i < c1; i += 1024) {
        int e = loadI(edges, i, imode);
        int v = loadI(vertex, i, imode);
        int be = e >> SE_LOG;
        int r  = atomicAdd(&cnt[be], 1);
        buck[gb[be] + r] = ((e & ((1 << SE_LOG) - 1)) << bitsN) | v;
        int bv = NBE + (v >> SV_LOG);
        int r2 = atomicAdd(&cnt[bv], 1);
        buck[gb[bv] + r2] = ((v & ((1 << SV_LOG) - 1)) << bitsE) | e;
    }
}

// -------- bfe: 2 blocks per edge-bucket, each handles 32 of 64 bins -----------
__global__ __launch_bounds__(512)
void bfe_kernel(const int* __restrict__ buck, const int* __restrict__ bbase,
                const float* __restrict__ homof, int* __restrict__ spill,
                const unsigned short* __restrict__ Xpb,
                unsigned short* __restrict__ Ye, int E, int bitsN) {
    __shared__ int list[CAPB];
    __shared__ int cnt[32];
    __shared__ int sexc[32];
    __shared__ int tot_s;
    int blk = blockIdx.x;
    int g = blk >> 1, half = blk & 1;
    int bin0f = g << SE_LOG;
    int nbf   = min(1 << SE_LOG, E - bin0f);
    int hb0   = half * 32;
    int nbh   = nbf - hb0; if (nbh > 32) nbh = 32;
    if (nbh <= 0) return;
    int s0 = bbase[g], s1 = bbase[g + 1], size = s1 - s0;
    int tid = threadIdx.x, lane = tid & 63, w = tid >> 6;
    int pmask = (1 << bitsN) - 1;
    if (tid < nbh) cnt[tid] = 0;
    __syncthreads();
    for (int j = tid; j < size; j += 512) {
        int lb = (buck[s0 + j] >> bitsN) - hb0;
        if ((unsigned)lb < (unsigned)nbh) atomicAdd(&cnt[lb], 1);
    }
    __syncthreads();
    if (w == 0) {   // scan over <=32 bins in wave 0
        int x = (lane < nbh) ? cnt[lane] : 0;
        int s = x;
#pragma unroll
        for (int d = 1; d < 64; d <<= 1) {
            int t = __shfl_up(s, d, 64);
            if (lane >= d) s += t;
        }
        if (lane < nbh) sexc[lane] = s - x;
        if (lane == nbh - 1) tot_s = s;
    }
    __syncthreads();
    int halfsize = tot_s;
    bool sp = (halfsize > CAPB);
    int soff = s0 + (half ? (size - halfsize) : 0);  // disjoint spill regions
    if (tid < nbh) cnt[tid] = sexc[tid];             // cursors
    __syncthreads();
    for (int j = tid; j < size; j += 512) {
        int p  = buck[s0 + j];
        int lb = (p >> bitsN) - hb0;
        if ((unsigned)lb < (unsigned)nbh) {
            int r = atomicAdd(&cnt[lb], 1);
            int v = p & pmask;
            if (sp) spill[soff + r] = v; else list[r] = v;
        }
    }
    __syncthreads();
    // compute: 32 groups x 16 lanes; group owns one edge; lane owns 4 channels
    int grp = tid >> 4;
    int c = tid & 15;
    unsigned co = (unsigned)c << 3;
    if (grp < nbh) {
        int start = sexc[grp], end = cnt[grp];
        const char* Xb = (const char*)Xpb;
        float a0 = 0.f, a1 = 0.f, a2 = 0.f, a3 = 0.f;
        int j = start;
        if (!sp) {
            for (; j + 3 < end; j += 4) {
                int v0 = list[j], v1 = list[j + 1], v2 = list[j + 2], v3 = list[j + 3];
                uint2 u0 = *(const uint2*)(Xb + (((unsigned)v0 << 7) + co));
                uint2 u1 = *(const uint2*)(Xb + (((unsigned)v1 << 7) + co));
                uint2 u2 = *(const uint2*)(Xb + (((unsigned)v2 << 7) + co));
                uint2 u3 = *(const uint2*)(Xb + (((unsigned)v3 << 7) + co));
                a0 += (bflo(u0.x) + bflo(u1.x)) + (bflo(u2.x) + bflo(u3.x));
                a1 += (bfhi(u0.x) + bfhi(u1.x)) + (bfhi(u2.x) + bfhi(u3.x));
                a2 += (bflo(u0.y) + bflo(u1.y)) + (bflo(u2.y) + bflo(u3.y));
                a3 += (bfhi(u0.y) + bfhi(u1.y)) + (bfhi(u2.y) + bfhi(u3.y));
            }
            for (; j < end; ++j) {
                int v = list[j];
                uint2 u = *(const uint2*)(Xb + (((unsigned)v << 7) + co));
                a0 += bflo(u.x); a1 += bfhi(u.x);
                a2 += bflo(u.y); a3 += bfhi(u.y);
            }
        } else {
            for (; j < end; ++j) {
                int v = spill[soff + j];
                uint2 u = *(const uint2*)(Xb + (((unsigned)v << 7) + co));
                a0 += bflo(u.x); a1 += bfhi(u.x);
                a2 += bflo(u.y); a3 += bfhi(u.y);
            }
        }
        int e = bin0f + hb0 + grp;
        float inv = homof[e] / fmaxf((float)(end - start), 1.f);
        unsigned p0 = (unsigned)f2bf(a0 * inv) | ((unsigned)f2bf(a1 * inv) << 16);
        unsigned p1 = (unsigned)f2bf(a2 * inv) | ((unsigned)f2bf(a3 * inv) << 16);
        *(uint2*)((char*)Ye + (((unsigned)e << 7) + co)) = make_uint2(p0, p1);
    }
}

// -------- bfv: 2 blocks per vertex-bucket, each handles 128 of 256 bins -------
__global__ __launch_bounds__(512)
void bfv_kernel(const int* __restrict__ buck, const int* __restrict__ bbase,
                const float* __restrict__ homof, int* __restrict__ spill,
                const unsigned short* __restrict__ Xpb,
                const unsigned short* __restrict__ Ye,
                float* __restrict__ out, int N, int NBE, int bitsE) {
    __shared__ int list[CAPB];
    __shared__ int cnt[128];
    __shared__ int sexc[128];
    __shared__ float hsum[128];
    __shared__ int wsum[8];
    __shared__ int tot_s;
    int blk = blockIdx.x;
    int bv = blk >> 1, half = blk & 1;
    int bin0f = bv << SV_LOG;
    int nbf   = min(1 << SV_LOG, N - bin0f);
    int hb0   = half * 128;
    int nbh   = nbf - hb0; if (nbh > 128) nbh = 128;
    if (nbh <= 0) return;
    int s0 = bbase[NBE + bv], s1 = bbase[NBE + bv + 1], size = s1 - s0;
    int tid = threadIdx.x, lane = tid & 63, w = tid >> 6;
    int pmask = (1 << bitsE) - 1;
    if (tid < nbh) { cnt[tid] = 0; hsum[tid] = 0.f; }
    __syncthreads();
    for (int j = tid; j < size; j += 512) {
        int lb = (buck[s0 + j] >> bitsE) - hb0;
        if ((unsigned)lb < (unsigned)nbh) atomicAdd(&cnt[lb], 1);
    }
    __syncthreads();
    {   // scan over <=128 bins (2 waves)
        int x = (tid < nbh) ? cnt[tid] : 0;
        int s = x;
#pragma unroll
        for (int d = 1; d < 64; d <<= 1) {
            int t = __shfl_up(s, d, 64);
            if (lane >= d) s += t;
        }
        if (lane == 63) wsum[w] = s;
        __syncthreads();
        if (w == 0 && lane < 8) {
            int v = wsum[lane];
#pragma unroll
            for (int d = 1; d < 8; d <<= 1) {
                int t = __shfl_up(v, d, 64);
                if (lane >= d) v += t;
            }
            wsum[lane] = v;
        }
        __syncthreads();
        int excl = s - x + (w > 0 ? wsum[w - 1] : 0);
        if (tid < nbh) sexc[tid] = excl;
        if (tid == nbh - 1) tot_s = excl + x;
    }
    __syncthreads();
    int halfsize = tot_s;
    bool sp = (halfsize > CAPB);
    int soff = s0 + (half ? (size - halfsize) : 0);
    if (tid < nbh) cnt[tid] = sexc[tid];
    __syncthreads();
    for (int j = tid; j < size; j += 512) {
        int p  = buck[s0 + j];
        int lb = (p >> bitsE) - hb0;
        if ((unsigned)lb < (unsigned)nbh) {
            int r = atomicAdd(&cnt[lb], 1);
            int e = p & pmask;
            if (sp) spill[soff + r] = e; else list[r] = e;
            atomicAdd(&hsum[lb], homof[e]);
        }
    }
    __syncthreads();
    // compute: 64 groups x 8 lanes; group owns vertices vl, vl+64
    int grp = tid >> 3;
    int c = tid & 7;
    unsigned co = (unsigned)c << 4;
    const char* Yb = (const char*)Ye;
    for (int vl = grp; vl < nbh; vl += 64) {
        int start = sexc[vl], end = cnt[vl];
        float a0 = 0.f, a1 = 0.f, a2 = 0.f, a3 = 0.f;
        float a4 = 0.f, a5 = 0.f, a6 = 0.f, a7 = 0.f;
        int j = start;
        if (!sp) {
            for (; j + 3 < end; j += 4) {
                int e0 = list[j], e1 = list[j + 1], e2 = list[j + 2], e3 = list[j + 3];
                uint4 u0 = *(const uint4*)(Yb + (((unsigned)e0 << 7) + co));
                uint4 u1 = *(const uint4*)(Yb + (((unsigned)e1 << 7) + co));
                uint4 u2 = *(const uint4*)(Yb + (((unsigned)e2 << 7) + co));
                uint4 u3 = *(const uint4*)(Yb + (((unsigned)e3 << 7) + co));
                a0 += (bflo(u0.x) + bflo(u1.x)) + (bflo(u2.x) + bflo(u3.x));
                a1 += (bfhi(u0.x) + bfhi(u1.x)) + (bfhi(u2.x) + bfhi(u3.x));
                a2 += (bflo(u0.y) + bflo(u1.y)) + (bflo(u2.y) + bflo(u3.y));
                a3 += (bfhi(u0.y) + bfhi(u1.y)) + (bfhi(u2.y) + bfhi(u3.y));
                a4 += (bflo(u0.z) + bflo(u1.z)) + (bflo(u2.z) + bflo(u3.z));
                a5 += (bfhi(u0.z) + bfhi(u1.z)) + (bfhi(u2.z) + bfhi(u3.z));
                a6 += (bflo(u0.w) + bflo(u1.w)) + (bflo(u2.w) + bflo(u3.w));
                a7 += (bfhi(u0.w) + bfhi(u1.w)) + (bfhi(u2.w) + bfhi(u3.w));
            }
            for (; j < end; ++j) {
                int e = list[j];
                uint4 u = *(const uint4*)(Yb + (((unsigned)e << 7) + co));
                a0 += bflo(u.x); a1 += bfhi(u.x);
                a2 += bflo(u.y); a3 += bfhi(u.y);
                a4 += bflo(u.z); a5 += bfhi(u.z);
                a6 += bflo(u.w); a7 += bfhi(u.w);
            }
        } else {
            for (; j < end; ++j) {
                int e = spill[soff + j];
                uint4 u = *(const uint4*)(Yb + (((unsigned)e << 7) + co));
                a0 += bflo(u.x); a1 += bfhi(u.x);
                a2 += bflo(u.y); a3 += bfhi(u.y);
                a4 += bflo(u.z); a5 += bfhi(u.z);
                a6 += bflo(u.w); a7 += bfhi(u.w);
            }
        }
        int vid = bin0f + hb0 + vl;
        float hsv = hsum[vl];
        float inv = (hsv > 0.f) ? 1.f / hsv : 0.f;
        uint4 xu = *(const uint4*)((const char*)Xpb + (((unsigned)vid << 7) + co));
        float r0 = bflo(xu.x) + a0 * inv, r1 = bfhi(xu.x) + a1 * inv;
        float r2 = bflo(xu.y) + a2 * inv, r3 = bfhi(xu.y) + a3 * inv;
        float r4 = bflo(xu.z) + a4 * inv, r5 = bfhi(xu.z) + a5 * inv;
        float r6 = bflo(xu.w) + a6 * inv, r7 = bfhi(xu.w) + a7 * inv;
        float ss = ((r0 * r0 + r1 * r1) + (r2 * r2 + r3 * r3)) +
                   ((r4 * r4 + r5 * r5) + (r6 * r6 + r7 * r7));
        ss += __shfl_xor(ss, 1, 64);
        ss += __shfl_xor(ss, 2, 64);
        ss += __shfl_xor(ss, 4, 64);
        float rn    = sqrtf(ss);
        float scale = (rn > 0.f) ? 1.f / fmaxf(rn, 1e-30f) : 0.f;
        char* ob = (char*)out + (((unsigned)vid << 8) + (co << 1));
        *(float4*)ob        = make_float4(r0 * scale, r1 * scale, r2 * scale, r3 * scale);
        *(float4*)(ob + 16) = make_float4(r4 * scale, r5 * scale, r6 * scale, r7 * scale);
    }
}

// ================= fallback path (old, verified kernels) =====================
__global__ void hist_atomic_kernel(const void* __restrict__ edges,
                                   const void* __restrict__ vertex,
                                   const int* __restrict__ flags,
                                   int* __restrict__ tot, int E, int nnz) {
    int i = blockIdx.x * blockDim.x + threadIdx.x;
    if (i >= nnz) return;
    int imode = flags[1];
    atomicAdd(&tot[loadI(edges, i, imode)], 1);
    atomicAdd(&tot[E + loadI(vertex, i, imode)], 1);
}

__global__ void scan_part_kernel(const int* __restrict__ tot, int* __restrict__ part, int M) {
    int g = blockIdx.x, tid = threadIdx.x;
    int base = g * 2048;
    int sum = 0;
    for (int j = tid; j < 2048; j += 256) {
        int i = base + j;
        sum += (i < M) ? tot[i] : 0;
    }
#pragma unroll
    for (int d = 32; d >= 1; d >>= 1) sum += __shfl_xor(sum, d, 64);
    __shared__ int wsums[4];
    int lane = tid & 63, w = tid >> 6;
    if (lane == 0) wsums[w] = sum;
    __syncthreads();
    if (tid == 0) part[g] = wsums[0] + wsums[1] + wsums[2] + wsums[3];
}

__global__ void scan_root_kernel(int* __restrict__ part, int G,
                                 int* __restrict__ off, int M) {
    int tid = threadIdx.x, lane = tid & 63, w = tid >> 6;
    int x = (tid < G) ? part[tid] : 0;
    int s = x;
#pragma unroll
    for (int d = 1; d < 64; d <<= 1) {
        int t = __shfl_up(s, d, 64);
        if (lane >= d) s += t;
    }
    __shared__ int ws[16];
    if (lane == 63) ws[w] = s;
    __syncthreads();
    if (w == 0 && lane < 16) {
        int v = ws[lane];
#pragma unroll
        for (int d = 1; d < 16; d <<= 1) {
            int t = __shfl_up(v, d, 64);
            if (lane >= d) v += t;
        }
        ws[lane] = v;
    }
    __syncthreads();
    int excl = s - x + (w > 0 ? ws[w - 1] : 0);
    if (tid < G) part[tid] = excl;
    if (tid == 1023) off[M] = ws[15];
}

__global__ void scan_apply_kernel(int* __restrict__ tot, const int* __restrict__ part,
                                  int* __restrict__ off, int M) {
    int g = blockIdx.x, tid = threadIdx.x, lane = tid & 63, w = tid >> 6;
    int base = g * 2048 + tid * 8;
    int e[8]; int s = 0;
#pragma unroll
    for (int j = 0; j < 8; ++j) {
        int i = base + j;
        e[j] = (i < M) ? tot[i] : 0;
        s += e[j];
    }
    int si = s;
#pragma unroll
    for (int d = 1; d < 64; d <<= 1) {
        int t = __shfl_up(si, d, 64);
        if (lane >= d) si += t;
    }
    __shared__ int wsum[4];
    if (lane == 63) wsum[w] = si;
    __syncthreads();
    int wbase = 0;
    for (int ww = 0; ww < w; ++ww) wbase += wsum[ww];
    int run = part[g] + wbase + si - s;
#pragma unroll
    for (int j = 0; j < 8; ++j) {
        int i = base + j;
        if (i < M) off[i] = run;
        run += e[j];
    }
}

__global__ void copy_kernel(const int* __restrict__ src, int* __restrict__ dst, int n) {
    int i = blockIdx.x * blockDim.x + threadIdx.x;
    if (i < n) dst[i] = src[i];
}

__global__ void scatter_atomic_kernel(const void* __restrict__ edges,
                                      const void* __restrict__ vertex,
                                      const int* __restrict__ flags,
                                      int* __restrict__ cur, int* __restrict__ dest,
                                      int E, int nnz) {
    int i = blockIdx.x * blockDim.x + threadIdx.x;
    if (i >= nnz) return;
    int imode = flags[1];
    int e = loadI(edges, i, imode);
    int v = loadI(vertex, i, imode);
    dest[atomicAdd(&cur[e], 1)]     = v;
    dest[atomicAdd(&cur[E + v], 1)] = e;
}

__global__ void hs_fallback_kernel(const int* __restrict__ off,
                                   const int* __restrict__ sorted,
                                   const float* __restrict__ homof,
                                   float* __restrict__ hs, int E, int N) {
    int v = blockIdx.x * blockDim.x + threadIdx.x;
    if (v >= N) return;
    int s = off[E + v], e = off[E + v + 1];
    float t = 0.f;
    for (int j = s; j < e; ++j) t += homof[sorted[j]];
    hs[v] = t;
}

__global__ void edge_mean_kernel(const unsigned short* __restrict__ Xpb,
                                 const int* __restrict__ off,
                                 const int* __restrict__ sorted,
                                 const float* __restrict__ homof,
                                 unsigned short* __restrict__ Ye, int E) {
    int wid  = (blockIdx.x * blockDim.x + threadIdx.x) >> 6;
    int lane = threadIdx.x & 63;
    if (wid >= E) return;
    int g = lane >> 4, c = lane & 15;
    unsigned co = (unsigned)c << 3;
    int start = off[wid], end = off[wid + 1];
    float a0 = 0.f, a1 = 0.f, a2 = 0.f, a3 = 0.f;
    const char* Xb = (const char*)Xpb;
    for (int j = start + g; j < end; j += 4) {
        int v = sorted[j];
        uint2 u = *(const uint2*)(Xb + (((unsigned)v << 7) + co));
        a0 += bflo(u.x); a1 += bfhi(u.x);
        a2 += bflo(u.y); a3 += bfhi(u.y);
    }
    a0 += __shfl_xor(a0, 16, 64); a0 += __shfl_xor(a0, 32, 64);
    a1 += __shfl_xor(a1, 16, 64); a1 += __shfl_xor(a1, 32, 64);
    a2 += __shfl_xor(a2, 16, 64); a2 += __shfl_xor(a2, 32, 64);
    a3 += __shfl_xor(a3, 16, 64); a3 += __shfl_xor(a3, 32, 64);
    if (g == 0) {
        float inv = homof[wid] / fmaxf((float)(end - start), 1.f);
        unsigned p0 = (unsigned)f2bf(a0 * inv) | ((unsigned)f2bf(a1 * inv) << 16);
        unsigned p1 = (unsigned)f2bf(a2 * inv) | ((unsigned)f2bf(a3 * inv) << 16);
        *(uint2*)((char*)Ye + (((unsigned)wid << 7) + co)) = make_uint2(p0, p1);
    }
}

__global__ void vertex_out_kernel(const unsigned short* __restrict__ Xpb,
                                  const unsigned short* __restrict__ Ye,
                                  const int* __restrict__ off,
                                  const int* __restrict__ sorted,
                                  const float* __restrict__ hs,
                                  float* __restrict__ out, int E, int N) {
    int wv   = (blockIdx.x * blockDim.x + threadIdx.x) >> 6;
    int lane = threadIdx.x & 63;
    int g = lane >> 3, c = lane & 7;
    int vid = wv * 8 + g;
    if (vid >= N) return;
    unsigned co = (unsigned)c << 4;
    int start = off[E + vid], end = off[E + vid + 1];
    float a0 = 0.f, a1 = 0.f, a2 = 0.f, a3 = 0.f;
    float a4 = 0.f, a5 = 0.f, a6 = 0.f, a7 = 0.f;
    const char* Yb = (const char*)Ye;
    for (int j = start; j < end; ++j) {
        int e = sorted[j];
        uint4 u = *(const uint4*)(Yb + (((unsigned)e << 7) + co));
        a0 += bflo(u.x); a1 += bfhi(u.x);
        a2 += bflo(u.y); a3 += bfhi(u.y);
        a4 += bflo(u.z); a5 += bfhi(u.z);
        a6 += bflo(u.w); a7 += bfhi(u.w);
    }
    float hsv = hs[vid];
    float inv = (hsv > 0.f) ? 1.f / hsv : 0.f;
    uint4 xu = *(const uint4*)((const char*)Xpb + (((unsigned)vid << 7) + co));
    float r0 = bflo(xu.x) + a0 * inv, r1 = bfhi(xu.x) + a1 * inv;
    float r2 = bflo(xu.y) + a2 * inv, r3 = bfhi(xu.y) + a3 * inv;
    float r4 = bflo(xu.z) + a4 * inv, r5 = bfhi(xu.z) + a5 * inv;
    float r6 = bflo(xu.w) + a6 * inv, r7 = bfhi(xu.w) + a7 * inv;
    float ss = ((r0 * r0 + r1 * r1) + (r2 * r2 + r3 * r3)) +
               ((r4 * r4 + r5 * r5) + (r6 * r6 + r7 * r7));
    ss += __shfl_xor(ss, 1, 64);
    ss += __shfl_xor(ss, 2, 64);
    ss += __shfl_xor(ss, 4, 64);
    float rn    = sqrtf(ss);
    float scale = (rn > 0.f) ? 1.f / fmaxf(rn, 1e-30f) : 0.f;
    char* ob = (char*)out + (((unsigned)vid << 8) + (co << 1));
    *(float4*)ob        = make_float4(r0 * scale, r1 * scale, r2 * scale, r3 * scale);
    *(float4*)(ob + 16) = make_float4(r4 * scale, r5 * scale, r6 * scale, r7 * scale);
}

static inline int ceil_bits(int n) {
    int v = n - 1;
    if (v < 1) v = 1;
    int b = 0;
    while ((1 << b) <= v) ++b;
    return b;
}

extern "C" void kernel_launch(void* const* d_in, const int* in_sizes, int n_in,
                              void* d_out, int out_size, void* d_ws, size_t ws_size,
                              hipStream_t stream) {
    const void* X      = d_in[0];
    const void* W      = d_in[1];
    const void* homo   = d_in[2];
    const void* vertex = d_in[3];
    const void* edges  = d_in[4];
    float* out = (float*)d_out;

    const int N   = in_sizes[0] / 64;
    const int E   = in_sizes[2];
    const int NNZ = in_sizes[3];
    const int M   = E + N;

    const int NBE = (E + (1 << SE_LOG) - 1) >> SE_LOG;
    const int NBV = (N + (1 << SV_LOG) - 1) >> SV_LOG;
    const int NBT = NBE + NBV;
    const int GC  = (NNZ + CH - 1) / CH;
    const int bitsN = ceil_bits(N);
    const int bitsE = ceil_bits(E);
    const int G   = (M + 2047) / 2048;  // fallback scan tiles

    char*  ws = (char*)d_ws;
    size_t o  = 0;
    auto alloc = [&](size_t bytes) -> void* {
        void* p = ws + o;
        o += (bytes + 255) & ~(size_t)255;
        return p;
    };
    int*            flags = (int*)alloc(2 * 4);
    int*            bbase = (int*)alloc((size_t)(NBT + 1) * 4);
    int*            bcur  = (int*)alloc((size_t)NBT * 4);
    int*            btot  = (int*)alloc((size_t)NBT * 4);
    float*          homof = (float*)alloc((size_t)E * 4);
    int*            buck  = (int*)alloc((size_t)2 * NNZ * 4);
    int*            spill = (int*)alloc((size_t)2 * NNZ * 4);  // fallback: sorted
    unsigned short* Xpb   = (unsigned short*)alloc((size_t)N * 64 * 2);
    unsigned short* Ye    = (unsigned short*)alloc((size_t)E * 64 * 2);
    int*            slabc = (int*)alloc((size_t)GC * NBT * 4);
    size_t o_common = o;
    bool fast = (o <= ws_size) && NBT <= 2048 &&
                (SE_LOG + bitsN <= 31) && (SV_LOG + bitsE <= 31) && G <= 1024;
    (void)n_in; (void)out_size;

    sniff_kernel<<<1, 64, 0, stream>>>(X, vertex, flags);
    homof_kernel<<<(E + 255) / 256, 256, 0, stream>>>(homo, flags, homof, E);
    gemm_mfma_kernel<<<1024, 256, 0, stream>>>((const unsigned short*)X,
                                               (const unsigned short*)W,
                                               flags, Xpb, N);
    gemm_f32_kernel<<<512, 256, 0, stream>>>(X, W, flags, Xpb, N);

    if (fast) {
        hipMemsetAsync(btot, 0, (size_t)NBT * 4, stream);
        bhist2_kernel<<<GC, 1024, 0, stream>>>(edges, vertex, flags, btot,
                                               slabc, NNZ, NBE, NBT);
        bscan_kernel<<<1, 1024, 0, stream>>>(btot, bbase, bcur, NBT);
        bscatter2_kernel<<<GC, 1024, 0, stream>>>(edges, vertex, flags, bcur,
                                                  slabc, buck, NNZ, NBE, NBT,
                                                  bitsN, bitsE);
        bfe_kernel<<<2 * NBE, 512, 0, stream>>>(buck, bbase, homof, spill,
                                                Xpb, Ye, E, bitsN);
        bfv_kernel<<<2 * NBV, 512, 0, stream>>>(buck, bbase, homof, spill,
                                                Xpb, Ye, out, N, NBE, bitsE);
    } else {
        o = o_common;
        int* off  = (int*)alloc((size_t)(M + 1) * 4);
        float* hs = (float*)alloc((size_t)N * 4);
        int* tot  = (int*)alloc((size_t)M * 4);
        int* part = (int*)alloc((size_t)(G + 1) * 4);
        int* cur  = (int*)alloc((size_t)M * 4);
        int* sorted = spill;
        hipMemsetAsync(tot, 0, (size_t)M * 4, stream);
        int nb = (NNZ + 255) / 256;
        hist_atomic_kernel<<<nb, 256, 0, stream>>>(edges, vertex, flags, tot, E, NNZ);
        scan_part_kernel<<<G, 256, 0, stream>>>(tot, part, M);
        scan_root_kernel<<<1, 1024, 0, stream>>>(part, G, off, M);
        scan_apply_kernel<<<G, 256, 0, stream>>>(tot, part, off, M);
        copy_kernel<<<(M + 255) / 256, 256, 0, stream>>>(off, cur, M);
        scatter_atomic_kernel<<<nb, 256, 0, stream>>>(edges, vertex, flags, cur, sorted, E, NNZ);
        hs_fallback_kernel<<<(N + 255) / 256, 256, 0, stream>>>(off, sorted, homof, hs, E, N);
        edge_mean_kernel<<<(E + 3) / 4, 256, 0, stream>>>(Xpb, off, sorted, homof, Ye, E);
        int vwaves  = (N + 7) / 8;
        int vblocks = (vwaves * 64 + 255) / 256;
        vertex_out_kernel<<<vblocks, 256, 0, stream>>>(Xpb, Ye, off, sorted, hs, out, E, N);
    }
}